// Round 5
// baseline (121.278 us; speedup 1.0000x reference)
//
#include <hip/hip_runtime.h>

// AugmentedTripletLoss on MI355X.
// inputs [8192,128] f32, targets [8192] int, center [16,128] f32 -> scalar loss.
//
// v7 = v6 with ONE change: __launch_bounds__(256, 1) on pairdist.
// Diagnosis: v5/v6 compiled to 128 VGPRs against ~210 live registers.
// launch_bounds(256,2) let the allocator chase a 16-waves/CU register
// target, SPILLING ~80 regs/thread to scratch (WRITE_SIZE 3.5 MB over
// outputs; VALUBusy 15%; duration insensitive to work reduction = scratch
// latency on the critical path). The v6 asm pins block remat but not
// spill. min-waves=1 raises the budget to 512 -> ~210 live regs fit with
// zero spill; occupancy stays 8 waves/CU (2 blocks/CU, m69: 129-256 VGPR
// band) so nothing is traded away. Signature to check: VGPR_Count ~200+.
// Everything else byte-identical to v6 (passed correctness twice):
// one-hot +-s class bias in the GEMM (K=192, branchless epilogue), T21
// both-sides XOR swizzle, 64-col double-buffered stages, symmetric tiling
// (496 off-diag + 16 diag-pair blocks = 512 = exactly 2/CU), prep fusion.

#define N_ROWS 8192
#define DIM 128
#define KDIM 192          // 128 data dims + 64 one-hot class dims
#define ROWB 384          // KDIM * 2 bytes (bf16)
#define NPROTO 16
#define NRG 32            // 256-row groups
#define MARGIN_F 1.0f
#define EPS_F 1e-12f
#define BIAS_F 32768.0f   // 2*s^2 with s=128 (exact in bf16: 0x4300)

typedef __attribute__((ext_vector_type(8))) short short8;   // 8 bf16 = 4 VGPRs
typedef __attribute__((ext_vector_type(4))) float float4v;  // MFMA acc
typedef __attribute__((ext_vector_type(4))) unsigned uint4v;

static __device__ __forceinline__ unsigned f2bf(float f) {
  // round-to-nearest-even bf16 (no NaN expected in this data)
  unsigned u = __float_as_uint(f);
  u += 0x7fffu + ((u >> 16) & 1u);
  return u >> 16;
}

// order-preserving float <-> unsigned key (for integer atomicMax/Min on LDS)
static __device__ __forceinline__ unsigned fkey(float f) {
  unsigned b = __float_as_uint(f);
  return (b & 0x80000000u) ? ~b : (b | 0x80000000u);
}
static __device__ __forceinline__ float funkey(unsigned k) {
  unsigned b = (k & 0x80000000u) ? (k & 0x7fffffffu) : ~k;
  return __uint_as_float(b);
}

static __device__ __forceinline__ void gload_lds16(const void* g, void* l) {
  __builtin_amdgcn_global_load_lds(
      (const __attribute__((address_space(1))) unsigned*)g,
      (__attribute__((address_space(3))) unsigned*)l, 16, 0, 0);
}

// 512 blocks x 16 rows. Fuses center normalization (redundant per block, 8 KB)
// + row prep: bf16 pack (data + one-hot), ||x||^2, min dist-to-center.
__global__ void prep_kernel(const float* __restrict__ x,
                            const float* __restrict__ center,
                            const int* __restrict__ tgt,
                            char* __restrict__ xbf,
                            float* __restrict__ sq,
                            float* __restrict__ mindc,
                            float* __restrict__ out) {
  __shared__ float scn[NPROTO * DIM];  // normalized prototypes, 8 KB
  int tid = threadIdx.x;
  if (blockIdx.x == 0 && tid == 0) out[0] = 0.0f;  // zero loss accumulator
  int rloc = tid >> 4, l = tid & 15;
  {
    float v[8];
    float ss = 0.f;
#pragma unroll
    for (int j = 0; j < 8; ++j) {
      v[j] = center[rloc * DIM + l * 8 + j];
      ss += v[j] * v[j];
    }
    // 16-lane groups are contiguous in the wave -> masks 1..8 stay in-group
#pragma unroll
    for (int m = 1; m < 16; m <<= 1) ss += __shfl_xor(ss, m, 64);
    float inv = 1.0f / sqrtf(ss);
#pragma unroll
    for (int j = 0; j < 8; ++j) scn[rloc * DIM + l * 8 + j] = v[j] * inv;
  }
  __syncthreads();

  int row = blockIdx.x * 16 + rloc;
  float4 v0 = ((const float4*)x)[row * 32 + l * 2];
  float4 v1 = ((const float4*)x)[row * 32 + l * 2 + 1];
  float ss = v0.x * v0.x + v0.y * v0.y + v0.z * v0.z + v0.w * v0.w +
             v1.x * v1.x + v1.y * v1.y + v1.z * v1.z + v1.w * v1.w;
  float dots[NPROTO];
#pragma unroll
  for (int p = 0; p < NPROTO; ++p) {
    const float* c = &scn[p * DIM + l * 8];
    dots[p] = v0.x * c[0] + v0.y * c[1] + v0.z * c[2] + v0.w * c[3] +
              v1.x * c[4] + v1.y * c[5] + v1.z * c[6] + v1.w * c[7];
  }
#pragma unroll
  for (int m = 1; m < 16; m <<= 1) {
    ss += __shfl_xor(ss, m, 64);
#pragma unroll
    for (int p = 0; p < NPROTO; ++p) dots[p] += __shfl_xor(dots[p], m, 64);
  }
  // data dims: row-major bf16, 384 B/row (first 256 B)
  uint4 pk;
  pk.x = f2bf(v0.x) | (f2bf(v0.y) << 16);
  pk.y = f2bf(v0.z) | (f2bf(v0.w) << 16);
  pk.z = f2bf(v1.x) | (f2bf(v1.y) << 16);
  pk.w = f2bf(v1.z) | (f2bf(v1.w) << 16);
  *(uint4*)(xbf + (size_t)row * ROWB + l * 16) = pk;
  // one-hot class dims (bytes 256..383): -128 (0xC300) at class slot.
  // B side uses the stored -s; A side flips sign in-register -> product -s^2.
  int cls = tgt[row];
  if (l < 8) {
    unsigned wv = (cls & 1) ? 0xC3000000u : 0x0000C300u;  // bf16 -128
    uint4 oh;
    oh.x = ((cls >> 1) == (l * 4 + 0)) ? wv : 0u;
    oh.y = ((cls >> 1) == (l * 4 + 1)) ? wv : 0u;
    oh.z = ((cls >> 1) == (l * 4 + 2)) ? wv : 0u;
    oh.w = ((cls >> 1) == (l * 4 + 3)) ? wv : 0u;
    *(uint4*)(xbf + (size_t)row * ROWB + 256 + l * 16) = oh;
  }
  if (l == 0) {
    float mind2 = INFINITY;
#pragma unroll
    for (int p = 0; p < NPROTO; ++p)
      mind2 = fminf(mind2, ss + 1.0f - 2.0f * dots[p]);  // cn is unit-norm
    sq[row] = ss;
    mindc[row] = fmaxf(sqrtf(fmaxf(mind2, 0.0f)), EPS_F);
  }
}

// Grid: 512 blocks = 16 diag-pair blocks + 496 off-diag tiles. Block = 4
// waves. Stage = 64 cols x 384 B = 24 KB, double-buffered (T21 swizzle).
// v' = sq - 2*dot' tracked; one-hot bias makes positives +32768.
// launch_bounds(256,1): register budget 512 -> ~210 live regs, ZERO spill.
__global__ __launch_bounds__(256, 1) void
pairdist_kernel(const char* __restrict__ xbf, const float* __restrict__ sq,
                float* __restrict__ pmax, float* __restrict__ pmin) {
  __shared__ __align__(16) char bl[2][24576];  // 2 x (64 cols x 384 B)
  __shared__ float cmaxw[4][256], cminw[4][256];  // off-diag col stats, 8 KB
  const int wave = threadIdx.x >> 6, lane = threadIdx.x & 63;
  const int q = lane >> 4, l16 = lane & 15;
  const int slot = threadIdx.x;

  // T21 staging offsets: LDS dest linear (wave-uniform base + lane*16); the
  // XOR swizzle o' = o ^ ((col&7)<<4) applied to the per-lane GLOBAL source
  // and to the ds_read address (same involution both sides).
  int soff[6];
#pragma unroll
  for (int r = 0; r < 6; ++r) {
    int o = r * 4096 + slot * 16;
    int c = o / ROWB;
    soff[r] = c * ROWB + ((o - c * ROWB) ^ ((c & 7) << 4));
  }
  int roffb[6];
#pragma unroll
  for (int kc = 0; kc < 6; ++kc)
    roffb[kc] = (l16 * ROWB + kc * 64 + q * 16) ^ ((l16 & 7) << 4);

  if (blockIdx.x >= 16) {
    // ================= off-diagonal tile (I < J) =================
    int t = blockIdx.x - 16, I = 0;
    while (t >= 31 - I) { t -= 31 - I; ++I; }
    const int J = I + 1 + t;
    const int rowbase = I * 256 + wave * 64;
    const int colbase = J * 256;
    const char* const srcstrip = xbf + (size_t)colbase * ROWB;

    auto stage = [&](int s, char* buf) {
      const char* g = srcstrip + (size_t)s * 24576;  // 64 cols * 384 B
#pragma unroll
      for (int r = 0; r < 6; ++r)
        gload_lds16(g + soff[r], buf + r * 4096 + wave * 1024);
    };
    stage(0, bl[0]);  // prefetch stage 0 under the A-fragment loads

    // A-frags: A[m=l16][k=q*8+j], 4 row-tiles x 6 k-chunks (last 2 = one-hot,
    // stored -s -> flip to +s so the MFMA product is -s^2).
    short8 a[4][6];
#pragma unroll
    for (int rt = 0; rt < 4; ++rt) {
      const char* ar = xbf + (size_t)(rowbase + rt * 16 + l16) * ROWB + q * 16;
#pragma unroll
      for (int kc = 0; kc < 6; ++kc) a[rt][kc] = *(const short8*)(ar + kc * 64);
#pragma unroll
      for (int kc = 4; kc < 6; ++kc) {
        uint4v u = __builtin_bit_cast(uint4v, a[rt][kc]);
        u ^= 0x80008000u;
        a[rt][kc] = __builtin_bit_cast(short8, u);
      }
    }
    // anti-remat pin: make the asm the opaque producer of each fragment so
    // the allocator cannot re-load them from global inside the K-loop.
#pragma unroll
    for (int rt = 0; rt < 4; ++rt)
#pragma unroll
      for (int kc = 0; kc < 6; ++kc)
        asm volatile("" : "+v"(a[rt][kc]));

    float sqr[16];  // row ||x||^2: acc elem (rt,r) is row rowbase+rt*16+q*4+r
#pragma unroll
    for (int rt = 0; rt < 4; ++rt)
#pragma unroll
      for (int r = 0; r < 4; ++r)
        sqr[rt * 4 + r] = sq[rowbase + rt * 16 + q * 4 + r];

    float maxp[16], minn[16];
#pragma unroll
    for (int i = 0; i < 16; ++i) { maxp[i] = -INFINITY; minn[i] = INFINITY; }

#pragma unroll 1
    for (int s = 0; s < 4; ++s) {
      __syncthreads();  // buf[s&1] staged (vmcnt drain) + prev compute done
      if (s + 1 < 4) stage(s + 1, bl[(s + 1) & 1]);  // lands under compute
      const char* cur = bl[s & 1];
      float sqs[4];
#pragma unroll
      for (int ss = 0; ss < 4; ++ss)
        sqs[ss] = sq[colbase + s * 64 + ss * 16 + l16];
      float cmx[4], cmn[4];
#pragma unroll
      for (int ss = 0; ss < 4; ++ss) {
        const char* bufp = cur + ss * 6144;
        short8 b[6];
#pragma unroll
        for (int kc = 0; kc < 6; ++kc) b[kc] = *(const short8*)(bufp + roffb[kc]);
        float4v acc[4];
#pragma unroll
        for (int rt = 0; rt < 4; ++rt) acc[rt] = (float4v){0.f, 0.f, 0.f, 0.f};
#pragma unroll
        for (int kc = 0; kc < 6; ++kc)
#pragma unroll
          for (int rt = 0; rt < 4; ++rt)  // 4 independent acc chains
            acc[rt] = __builtin_amdgcn_mfma_f32_16x16x32_bf16(a[rt][kc], b[kc],
                                                              acc[rt], 0, 0, 0);
        // C/D layout: col = lane&15, row = q*4 + reg (m89-verified).
        // Row-part: v = sq_c - 2dot (finalize adds sq_r); branchless via bias.
#pragma unroll
        for (int rt = 0; rt < 4; ++rt)
#pragma unroll
          for (int r = 0; r < 4; ++r) {
            float v = fmaf(-2.0f, acc[rt][r], sqs[ss]);
            int idx = rt * 4 + r;
            maxp[idx] = fmaxf(maxp[idx], v);
            minn[idx] = fminf(minn[idx], v);
          }
        // Col-part: all 16 acc share col = l16 -> in-register 16-deep tree;
        // u = sq_r - 2dot (finalize adds sq_c for the col's row index).
        {
          float um = -INFINITY, un = INFINITY;
#pragma unroll
          for (int rt = 0; rt < 4; ++rt)
#pragma unroll
            for (int r = 0; r < 4; ++r) {
              float u = fmaf(-2.0f, acc[rt][r], sqr[rt * 4 + r]);
              um = fmaxf(um, u);
              un = fminf(un, u);
            }
          cmx[ss] = um;
          cmn[ss] = un;
        }
      }
      // fold col stats across q-groups (rows), park in LDS
#pragma unroll
      for (int ss = 0; ss < 4; ++ss) {
        float a1 = fmaxf(cmx[ss], __shfl_xor(cmx[ss], 16, 64));
        a1 = fmaxf(a1, __shfl_xor(a1, 32, 64));
        float a2 = fminf(cmn[ss], __shfl_xor(cmn[ss], 16, 64));
        a2 = fminf(a2, __shfl_xor(a2, 32, 64));
        if (q == 0) {
          cmaxw[wave][s * 64 + ss * 16 + l16] = a1;
          cminw[wave][s * 64 + ss * 16 + l16] = a2;
        }
      }
    }

    // Row-part: reduce across the 16 lanes of each quad (masks 1..8 in-group)
#pragma unroll
    for (int m = 1; m < 16; m <<= 1)
#pragma unroll
      for (int i = 0; i < 16; ++i) {
        maxp[i] = fmaxf(maxp[i], __shfl_xor(maxp[i], m, 64));
        minn[i] = fminf(minn[i], __shfl_xor(minn[i], m, 64));
      }
    if (l16 == 0) {  // waves own disjoint rows -> direct store to slab J
      float* pM = pmax + (size_t)J * N_ROWS + rowbase + q * 4;
      float* pm = pmin + (size_t)J * N_ROWS + rowbase + q * 4;
#pragma unroll
      for (int rt = 0; rt < 4; ++rt)
#pragma unroll
        for (int r = 0; r < 4; ++r) {
          pM[rt * 16 + r] = maxp[rt * 4 + r];
          pm[rt * 16 + r] = minn[rt * 4 + r];
        }
    }
    // Col-part: combine the 4 waves' partials, store slab I at rows J*256+c
    __syncthreads();
    {
      int c = threadIdx.x;
      float M = fmaxf(fmaxf(cmaxw[0][c], cmaxw[1][c]),
                      fmaxf(cmaxw[2][c], cmaxw[3][c]));
      float m = fminf(fminf(cminw[0][c], cminw[1][c]),
                      fminf(cminw[2][c], cminw[3][c]));
      pmax[(size_t)I * N_ROWS + colbase + c] = M;
      pmin[(size_t)I * N_ROWS + colbase + c] = m;
    }
  } else {
    // ======= diagonal pair block: tiles (G,G) for G = b and 31-b =======
    // Only the upper triangle of 16x16-col sub-tiles is computed (53% work).
    // Wave w owns row-tiles {w, 7-w, 8+w, 15-w}: 34 active rt-steps each.
    // Row r's final stat combines row-parts and col-parts -> merge through
    // LDS integer atomics on order-preserving keys.
    unsigned* dmax = (unsigned*)cmaxw;  // 256 keys (1 KB, aliases col arrays)
    unsigned* dmin = (unsigned*)cminw;
    int rtgs[4] = {wave, 7 - wave, 8 + wave, 15 - wave};

#pragma unroll 1
    for (int g2 = 0; g2 < 2; ++g2) {
      const int G = g2 ? (31 - (int)blockIdx.x) : (int)blockIdx.x;
      const int base = G * 256;
      const char* const srcstrip = xbf + (size_t)base * ROWB;
      dmax[threadIdx.x] = 0u;            // smallest key
      dmin[threadIdx.x] = 0xFFFFFFFFu;   // largest key

      auto stage = [&](int s, char* buf) {
        const char* g = srcstrip + (size_t)s * 24576;
#pragma unroll
        for (int r = 0; r < 6; ++r)
          gload_lds16(g + soff[r], buf + r * 4096 + wave * 1024);
      };
      stage(0, bl[0]);

      short8 a[4][6];
#pragma unroll
      for (int rt = 0; rt < 4; ++rt) {
        const char* ar =
            xbf + (size_t)(base + rtgs[rt] * 16 + l16) * ROWB + q * 16;
#pragma unroll
        for (int kc = 0; kc < 6; ++kc)
          a[rt][kc] = *(const short8*)(ar + kc * 64);
#pragma unroll
        for (int kc = 4; kc < 6; ++kc) {
          uint4v u = __builtin_bit_cast(uint4v, a[rt][kc]);
          u ^= 0x80008000u;
          a[rt][kc] = __builtin_bit_cast(short8, u);
        }
      }
#pragma unroll
      for (int rt = 0; rt < 4; ++rt)
#pragma unroll
        for (int kc = 0; kc < 6; ++kc)
          asm volatile("" : "+v"(a[rt][kc]));  // anti-remat pin

      float sqr[16];
#pragma unroll
      for (int rt = 0; rt < 4; ++rt)
#pragma unroll
        for (int r = 0; r < 4; ++r)
          sqr[rt * 4 + r] = sq[base + rtgs[rt] * 16 + q * 4 + r];

      float maxp[16], minn[16];
#pragma unroll
      for (int i = 0; i < 16; ++i) { maxp[i] = -INFINITY; minn[i] = INFINITY; }

#pragma unroll 1
      for (int s = 0; s < 4; ++s) {
        __syncthreads();  // staged data ready (vmcnt drain) + key init vis
        if (s + 1 < 4) stage(s + 1, bl[(s + 1) & 1]);
        const char* cur = bl[s & 1];
        float sqs[4];
#pragma unroll
        for (int ss = 0; ss < 4; ++ss)
          sqs[ss] = sq[base + s * 64 + ss * 16 + l16];
#pragma unroll
        for (int ss = 0; ss < 4; ++ss) {
          const int ct = s * 4 + ss;  // global col-tile index (wave-uniform)
          const char* bufp = cur + ss * 6144;
          short8 b[6];
#pragma unroll
          for (int kc = 0; kc < 6; ++kc)
            b[kc] = *(const short8*)(bufp + roffb[kc]);
          float4v acc[4];
          // MFMA only for active row-tiles (rtg <= ct); uniform branches
#pragma unroll
          for (int rt = 0; rt < 4; ++rt)
            if (rtgs[rt] <= ct) {
              acc[rt] = (float4v){0.f, 0.f, 0.f, 0.f};
#pragma unroll
              for (int kc = 0; kc < 6; ++kc)
                acc[rt] = __builtin_amdgcn_mfma_f32_16x16x32_bf16(
                    a[rt][kc], b[kc], acc[rt], 0, 0, 0);
            }
          // row-part (rtg <= ct): accumulate into maxp/minn
#pragma unroll
          for (int rt = 0; rt < 4; ++rt)
            if (rtgs[rt] <= ct)
#pragma unroll
              for (int r = 0; r < 4; ++r) {
                float v = fmaf(-2.0f, acc[rt][r], sqs[ss]);
                int idx = rt * 4 + r;
                maxp[idx] = fmaxf(maxp[idx], v);
                minn[idx] = fminf(minn[idx], v);
              }
          // col-part (rtg < ct): stat for row base+ct*16+l16 over the
          // wave's active rows; u = sq_r - 2dot
          bool any = false;
          float um = -INFINITY, un = INFINITY;
#pragma unroll
          for (int rt = 0; rt < 4; ++rt)
            if (rtgs[rt] < ct) {
              any = true;
#pragma unroll
              for (int r = 0; r < 4; ++r) {
                float u = fmaf(-2.0f, acc[rt][r], sqr[rt * 4 + r]);
                um = fmaxf(um, u);
                un = fminf(un, u);
              }
            }
          if (any) {  // wave-uniform
            um = fmaxf(um, __shfl_xor(um, 16, 64));
            um = fmaxf(um, __shfl_xor(um, 32, 64));
            un = fminf(un, __shfl_xor(un, 16, 64));
            un = fminf(un, __shfl_xor(un, 32, 64));
            if (q == 0) {
              atomicMax(&dmax[ct * 16 + l16], fkey(um));
              atomicMin(&dmin[ct * 16 + l16], fkey(un));
            }
          }
        }
      }
      // row-part: fold over the 16 cols of each quad, merge via atomics
#pragma unroll
      for (int m = 1; m < 16; m <<= 1)
#pragma unroll
        for (int i = 0; i < 16; ++i) {
          maxp[i] = fmaxf(maxp[i], __shfl_xor(maxp[i], m, 64));
          minn[i] = fminf(minn[i], __shfl_xor(minn[i], m, 64));
        }
      if (l16 == 0) {
#pragma unroll
        for (int rt = 0; rt < 4; ++rt)
#pragma unroll
          for (int r = 0; r < 4; ++r) {
            int rl = rtgs[rt] * 16 + q * 4 + r;
            atomicMax(&dmax[rl], fkey(maxp[rt * 4 + r]));
            atomicMin(&dmin[rl], fkey(minn[rt * 4 + r]));
          }
      }
      __syncthreads();  // all atomics done
      {
        int c = threadIdx.x;
        pmax[(size_t)G * N_ROWS + base + c] = funkey(dmax[c]);
        pmin[(size_t)G * N_ROWS + base + c] = funkey(dmin[c]);
      }
      if (g2 == 0) __syncthreads();  // reads done before re-init next group
    }
  }
}

__global__ void finalize_kernel(const float* __restrict__ pmax,
                                const float* __restrict__ pmin,
                                const float* __restrict__ sq,
                                const float* __restrict__ mindc,
                                float* __restrict__ out) {
  __shared__ float wsum[4];
  int i = blockIdx.x * 256 + threadIdx.x;  // 32 blocks x 256 = 8192 rows
  float maxv = -INFINITY, minv = INFINITY;
#pragma unroll
  for (int s = 0; s < NRG; ++s) {
    maxv = fmaxf(maxv, pmax[s * N_ROWS + i]);
    minv = fminf(minv, pmin[s * N_ROWS + i]);
  }
  float si = sq[i];
  float dap = sqrtf(fmaxf(si + (maxv - BIAS_F), EPS_F));  // un-bias positives
  // negatives are unbiased (< ~2000); if none exist anywhere, minv is the
  // biased positive min (~32768) -> fall back to dap + margin
  float dan = (minv > 16384.0f) ? (dap + MARGIN_F)
                                : sqrtf(fmaxf(si + minv, EPS_F));
  dan = fminf(dan, mindc[i]);
  float c = fmaxf(dap - dan + MARGIN_F, 0.0f) * (1.0f / (float)N_ROWS);
#pragma unroll
  for (int m = 1; m < 64; m <<= 1) c += __shfl_xor(c, m, 64);
  int lane = threadIdx.x & 63, wv = threadIdx.x >> 6;
  if (lane == 0) wsum[wv] = c;
  __syncthreads();
  if (threadIdx.x == 0) atomicAdd(out, wsum[0] + wsum[1] + wsum[2] + wsum[3]);
}

extern "C" void kernel_launch(void* const* d_in, const int* in_sizes, int n_in,
                              void* d_out, int out_size, void* d_ws, size_t ws_size,
                              hipStream_t stream) {
  const float* inputs = (const float*)d_in[0];
  const int* targets = (const int*)d_in[1];  // per harness: integer -> const int*
  const float* center = (const float*)d_in[2];
  char* ws = (char*)d_ws;
  // ws layout (all 256B-aligned):
  char* xbf    = ws;                       // 8192*384 B bf16+onehot = 3 MB
  float* sq    = (float*)(ws + 3145728);   // 8192 f32 = 32 KB
  float* mindc = (float*)(ws + 3178496);   // 8192 f32 = 32 KB
  float* pmax  = (float*)(ws + 3211264);   // 32*8192 f32 = 1 MB
  float* pmin  = (float*)(ws + 4259840);   // 32*8192 f32 = 1 MB
  float* out   = (float*)d_out;

  prep_kernel<<<512, 256, 0, stream>>>(inputs, center, targets, xbf, sq, mindc, out);
  pairdist_kernel<<<512, 256, 0, stream>>>(xbf, sq, pmax, pmin);
  finalize_kernel<<<32, 256, 0, stream>>>(pmax, pmin, sq, mindc, out);
}

// Round 6
// 91.868 us; speedup vs baseline: 1.3201x; 1.3201x over previous
//
#include <hip/hip_runtime.h>

// AugmentedTripletLoss on MI355X.
// inputs [8192,128] f32, targets [8192] int, center [16,128] f32 -> scalar loss.
//
// v8: revert to v4 (best-known: 93.0 us total; symmetric v5/v6/v7 all lost)
// and attack the diagnosed regime: latency-bound, in-phase waves, 8 waves/CU.
// Counters across v2..v7: MFMA-busy ~4.6us + VALU-busy ~8us inside a ~49us
// envelope -> ~85% wave-idle. Fix = TLP + phase heterogeneity:
//   - wave owns 2 row-tiles (a[2][6]=48 regs, core live ~120) and
//     __launch_bounds__(256,4) caps VGPR at 128 -> 4 waves/SIMD (no spill
//     by construction, v5's disease avoided by actually fitting).
//   - 32-col stages (2 x 12 KB LDS) -> 4 blocks/CU = 16 waves/CU, four
//     INDEPENDENT barrier groups per CU at different phases.
//   - block = 128 rows x 512-col strip, grid = 64 x 16 = 1024.
//   - T5 setprio(1) around the MFMA cluster (role diversity now exists).
// Kept verified pieces: one-hot +-s class bias in the GEMM (K=192,
// branchless epilogue), T21 both-sides XOR swizzle, double-buffered
// global_load_lds staging, prep fusion, 16-strip slab reduce.

#define N_ROWS 8192
#define DIM 128
#define KDIM 192          // 128 data dims + 64 one-hot class dims
#define ROWB 384          // KDIM * 2 bytes (bf16)
#define NPROTO 16
#define NSTRIP 16         // 512-col strips
#define NSTAGE 16         // 32-col stages per strip
#define MARGIN_F 1.0f
#define EPS_F 1e-12f
#define BIAS_F 32768.0f   // 2*s^2 with s=128 (exact in bf16: 0x4300)

typedef __attribute__((ext_vector_type(8))) short short8;   // 8 bf16 = 4 VGPRs
typedef __attribute__((ext_vector_type(4))) float float4v;  // MFMA acc
typedef __attribute__((ext_vector_type(4))) unsigned uint4v;

static __device__ __forceinline__ unsigned f2bf(float f) {
  // round-to-nearest-even bf16 (no NaN expected in this data)
  unsigned u = __float_as_uint(f);
  u += 0x7fffu + ((u >> 16) & 1u);
  return u >> 16;
}

static __device__ __forceinline__ void gload_lds16(const void* g, void* l) {
  __builtin_amdgcn_global_load_lds(
      (const __attribute__((address_space(1))) unsigned*)g,
      (__attribute__((address_space(3))) unsigned*)l, 16, 0, 0);
}

// 512 blocks x 16 rows. Fuses center normalization (redundant per block, 8 KB)
// + row prep: bf16 pack (data + one-hot), ||x||^2, min dist-to-center.
__global__ void prep_kernel(const float* __restrict__ x,
                            const float* __restrict__ center,
                            const int* __restrict__ tgt,
                            char* __restrict__ xbf,
                            float* __restrict__ sq,
                            float* __restrict__ mindc,
                            float* __restrict__ out) {
  __shared__ float scn[NPROTO * DIM];  // normalized prototypes, 8 KB
  int tid = threadIdx.x;
  if (blockIdx.x == 0 && tid == 0) out[0] = 0.0f;  // zero loss accumulator
  int rloc = tid >> 4, l = tid & 15;
  {
    float v[8];
    float ss = 0.f;
#pragma unroll
    for (int j = 0; j < 8; ++j) {
      v[j] = center[rloc * DIM + l * 8 + j];
      ss += v[j] * v[j];
    }
    // 16-lane groups are contiguous in the wave -> masks 1..8 stay in-group
#pragma unroll
    for (int m = 1; m < 16; m <<= 1) ss += __shfl_xor(ss, m, 64);
    float inv = 1.0f / sqrtf(ss);
#pragma unroll
    for (int j = 0; j < 8; ++j) scn[rloc * DIM + l * 8 + j] = v[j] * inv;
  }
  __syncthreads();

  int row = blockIdx.x * 16 + rloc;
  float4 v0 = ((const float4*)x)[row * 32 + l * 2];
  float4 v1 = ((const float4*)x)[row * 32 + l * 2 + 1];
  float ss = v0.x * v0.x + v0.y * v0.y + v0.z * v0.z + v0.w * v0.w +
             v1.x * v1.x + v1.y * v1.y + v1.z * v1.z + v1.w * v1.w;
  float dots[NPROTO];
#pragma unroll
  for (int p = 0; p < NPROTO; ++p) {
    const float* c = &scn[p * DIM + l * 8];
    dots[p] = v0.x * c[0] + v0.y * c[1] + v0.z * c[2] + v0.w * c[3] +
              v1.x * c[4] + v1.y * c[5] + v1.z * c[6] + v1.w * c[7];
  }
#pragma unroll
  for (int m = 1; m < 16; m <<= 1) {
    ss += __shfl_xor(ss, m, 64);
#pragma unroll
    for (int p = 0; p < NPROTO; ++p) dots[p] += __shfl_xor(dots[p], m, 64);
  }
  // data dims: row-major bf16, 384 B/row (first 256 B)
  uint4 pk;
  pk.x = f2bf(v0.x) | (f2bf(v0.y) << 16);
  pk.y = f2bf(v0.z) | (f2bf(v0.w) << 16);
  pk.z = f2bf(v1.x) | (f2bf(v1.y) << 16);
  pk.w = f2bf(v1.z) | (f2bf(v1.w) << 16);
  *(uint4*)(xbf + (size_t)row * ROWB + l * 16) = pk;
  // one-hot class dims (bytes 256..383): -128 (0xC300) at class slot.
  // B side uses the stored -s; A side flips sign in-register -> product -s^2.
  int cls = tgt[row];
  if (l < 8) {
    unsigned wv = (cls & 1) ? 0xC3000000u : 0x0000C300u;  // bf16 -128
    uint4 oh;
    oh.x = ((cls >> 1) == (l * 4 + 0)) ? wv : 0u;
    oh.y = ((cls >> 1) == (l * 4 + 1)) ? wv : 0u;
    oh.z = ((cls >> 1) == (l * 4 + 2)) ? wv : 0u;
    oh.w = ((cls >> 1) == (l * 4 + 3)) ? wv : 0u;
    *(uint4*)(xbf + (size_t)row * ROWB + 256 + l * 16) = oh;
  }
  if (l == 0) {
    float mind2 = INFINITY;
#pragma unroll
    for (int p = 0; p < NPROTO; ++p)
      mind2 = fminf(mind2, ss + 1.0f - 2.0f * dots[p]);  // cn is unit-norm
    sq[row] = ss;
    mindc[row] = fmaxf(sqrtf(fmaxf(mind2, 0.0f)), EPS_F);
  }
}

// Grid: 64 row-groups (128 rows) x 16 strips (512 cols) = 1024 blocks.
// Block = 4 waves; wave w owns rows rg*128+w*32..+31 (2 row-tiles); all
// waves share the LDS-staged B tile (32 cols x 384 B, double-buffered).
// 16 stages x 2 sub-steps. v' = sq_c - 2*dot' tracked (sqrt deferred);
// one-hot bias makes positives = v + 32768 -> branchless max/min epilogue.
__global__ __launch_bounds__(256, 4) void
pairdist_kernel(const char* __restrict__ xbf, const float* __restrict__ sq,
                float* __restrict__ pmax, float* __restrict__ pmin) {
  __shared__ __align__(16) char bl[2][12288];  // 2 x (32 cols x 384 B)
  const int bid = blockIdx.x;
  const int rg = bid >> 4;
  const int strip = bid & 15;
  const int wave = threadIdx.x >> 6, lane = threadIdx.x & 63;
  const int q = lane >> 4, l16 = lane & 15;
  const int rowbase = rg * 128 + wave * 32;
  const int stripbase = strip * 512;

  // Staging: 3 rounds x 4 KB (all 256 threads). LDS dest is linear
  // (wave-uniform base + lane*16, T21); the XOR swizzle o' = o ^ ((col&7)<<4)
  // is applied to the per-lane GLOBAL source address here and to the ds_read
  // address below (same involution both sides).
  const int slot = threadIdx.x;
  const char* const srcstrip = xbf + (size_t)stripbase * ROWB;
  int soff[3];
#pragma unroll
  for (int r = 0; r < 3; ++r) {
    int o = r * 4096 + slot * 16;
    int c = o / ROWB;
    soff[r] = c * ROWB + ((o - c * ROWB) ^ ((c & 7) << 4));
  }

  auto stage = [&](int s, char* buf) {
    const char* g = srcstrip + (size_t)s * 12288;  // 32 cols * 384 B per stage
#pragma unroll
    for (int r = 0; r < 3; ++r)
      gload_lds16(g + soff[r], buf + r * 4096 + wave * 1024);
  };

  stage(0, bl[0]);  // prefetch stage 0 under the A-fragment loads

  // A-frags: A[m=l16][k=q*8+j], 2 row-tiles x 6 k-chunks (last 2 = one-hot,
  // stored -s -> flip sign to +s so the MFMA product is -s^2).
  short8 a[2][6];
#pragma unroll
  for (int rt = 0; rt < 2; ++rt) {
    const char* ar = xbf + (size_t)(rowbase + rt * 16 + l16) * ROWB + q * 16;
#pragma unroll
    for (int kc = 0; kc < 6; ++kc) a[rt][kc] = *(const short8*)(ar + kc * 64);
#pragma unroll
    for (int kc = 4; kc < 6; ++kc) {
      uint4v u = __builtin_bit_cast(uint4v, a[rt][kc]);
      u ^= 0x80008000u;
      a[rt][kc] = __builtin_bit_cast(short8, u);
    }
  }
  // anti-remat pin (v5 lesson): asm is the opaque producer -> no global
  // re-load of fragments inside the K-loop.
#pragma unroll
  for (int rt = 0; rt < 2; ++rt)
#pragma unroll
    for (int kc = 0; kc < 6; ++kc)
      asm volatile("" : "+v"(a[rt][kc]));

  // Swizzled LDS read offsets. Sub-step ss reads buffer col cc = ss*16+l16;
  // cc&7 == l16&7, so the ss term (ss*6144) is additive outside the XOR.
  int roffb[6];
#pragma unroll
  for (int kc = 0; kc < 6; ++kc)
    roffb[kc] = (l16 * ROWB + kc * 64 + q * 16) ^ ((l16 & 7) << 4);

  float maxp[8], minn[8];
#pragma unroll
  for (int i = 0; i < 8; ++i) { maxp[i] = -INFINITY; minn[i] = INFINITY; }

#pragma unroll 1
  for (int s = 0; s < NSTAGE; ++s) {
    __syncthreads();  // buf[s&1] staged (vmcnt drain) + prev compute done
    if (s + 1 < NSTAGE) stage(s + 1, bl[(s + 1) & 1]);  // lands under compute
    const char* cur = bl[s & 1];
    float sqs[2];  // hoisted col ||x||^2 for both sub-steps
#pragma unroll
    for (int ss = 0; ss < 2; ++ss)
      sqs[ss] = sq[stripbase + s * 32 + ss * 16 + l16];
#pragma unroll
    for (int ss = 0; ss < 2; ++ss) {
      const char* bufp = cur + ss * 6144;
      short8 b[6];
#pragma unroll
      for (int kc = 0; kc < 6; ++kc) b[kc] = *(const short8*)(bufp + roffb[kc]);
      float4v acc[2];
#pragma unroll
      for (int rt = 0; rt < 2; ++rt) acc[rt] = (float4v){0.f, 0.f, 0.f, 0.f};
      __builtin_amdgcn_s_setprio(1);  // T5: favor the MFMA cluster
#pragma unroll
      for (int kc = 0; kc < 6; ++kc)
#pragma unroll
        for (int rt = 0; rt < 2; ++rt)  // 2 independent acc chains
          acc[rt] = __builtin_amdgcn_mfma_f32_16x16x32_bf16(a[rt][kc], b[kc],
                                                            acc[rt], 0, 0, 0);
      __builtin_amdgcn_s_setprio(0);
      // C/D layout: col = lane&15, row = q*4 + reg (m89-verified).
      // Branchless: positives carry +32768 bias, so max/min need no compare.
#pragma unroll
      for (int rt = 0; rt < 2; ++rt)
#pragma unroll
        for (int r = 0; r < 4; ++r) {
          float v = fmaf(-2.0f, acc[rt][r], sqs[ss]);  // dist2 = sq_row + v
          int idx = rt * 4 + r;
          maxp[idx] = fmaxf(maxp[idx], v);
          minn[idx] = fminf(minn[idx], v);
        }
    }
  }

  // reduce across the 16 lanes of each quad (xor masks 1..8 stay in-group)
#pragma unroll
  for (int m = 1; m < 16; m <<= 1)
#pragma unroll
    for (int i = 0; i < 8; ++i) {
      maxp[i] = fmaxf(maxp[i], __shfl_xor(maxp[i], m, 64));
      minn[i] = fminf(minn[i], __shfl_xor(minn[i], m, 64));
    }
  // waves own disjoint rows -> no cross-wave reduce; direct scattered store
  if (l16 == 0) {
    float* pM = pmax + (size_t)strip * N_ROWS + rowbase + q * 4;
    float* pm = pmin + (size_t)strip * N_ROWS + rowbase + q * 4;
#pragma unroll
    for (int rt = 0; rt < 2; ++rt)
#pragma unroll
      for (int r = 0; r < 4; ++r) {
        pM[rt * 16 + r] = maxp[rt * 4 + r];
        pm[rt * 16 + r] = minn[rt * 4 + r];
      }
  }
}

__global__ void finalize_kernel(const float* __restrict__ pmax,
                                const float* __restrict__ pmin,
                                const float* __restrict__ sq,
                                const float* __restrict__ mindc,
                                float* __restrict__ out) {
  __shared__ float wsum[4];
  int i = blockIdx.x * 256 + threadIdx.x;  // 32 blocks x 256 = 8192 rows
  float maxv = -INFINITY, minv = INFINITY;
#pragma unroll
  for (int s = 0; s < NSTRIP; ++s) {
    maxv = fmaxf(maxv, pmax[s * N_ROWS + i]);
    minv = fminf(minv, pmin[s * N_ROWS + i]);
  }
  float si = sq[i];
  float dap = sqrtf(fmaxf(si + (maxv - BIAS_F), EPS_F));  // un-bias positives
  // negatives are unbiased (< ~2000); if none exist anywhere, minv is the
  // biased positive min (~32768) -> fall back to dap + margin
  float dan = (minv > 16384.0f) ? (dap + MARGIN_F)
                                : sqrtf(fmaxf(si + minv, EPS_F));
  dan = fminf(dan, mindc[i]);
  float c = fmaxf(dap - dan + MARGIN_F, 0.0f) * (1.0f / (float)N_ROWS);
#pragma unroll
  for (int m = 1; m < 64; m <<= 1) c += __shfl_xor(c, m, 64);
  int lane = threadIdx.x & 63, wv = threadIdx.x >> 6;
  if (lane == 0) wsum[wv] = c;
  __syncthreads();
  if (threadIdx.x == 0) atomicAdd(out, wsum[0] + wsum[1] + wsum[2] + wsum[3]);
}

extern "C" void kernel_launch(void* const* d_in, const int* in_sizes, int n_in,
                              void* d_out, int out_size, void* d_ws, size_t ws_size,
                              hipStream_t stream) {
  const float* inputs = (const float*)d_in[0];
  const int* targets = (const int*)d_in[1];  // per harness: integer -> const int*
  const float* center = (const float*)d_in[2];
  char* ws = (char*)d_ws;
  // ws layout (all 256B-aligned):
  char* xbf    = ws;                       // 8192*384 B bf16+onehot = 3 MB
  float* sq    = (float*)(ws + 3145728);   // 8192 f32 = 32 KB
  float* mindc = (float*)(ws + 3178496);   // 8192 f32 = 32 KB
  float* pmax  = (float*)(ws + 3211264);   // 16*8192 f32 = 512 KB
  float* pmin  = (float*)(ws + 3735552);   // 16*8192 f32 = 512 KB
  float* out   = (float*)d_out;

  prep_kernel<<<512, 256, 0, stream>>>(inputs, center, targets, xbf, sq, mindc, out);
  pairdist_kernel<<<1024, 256, 0, stream>>>(xbf, sq, pmax, pmin);
  finalize_kernel<<<32, 256, 0, stream>>>(pmax, pmin, sq, mindc, out);
}